// Round 18
// baseline (117.107 us; speedup 1.0000x reference)
//
#include <hip/hip_runtime.h>
#include <math.h>

#define BATCH 4
#define NPTS 8192
#define GS 24                  // 24^3 cells of 0.5 over [-6,6]^3
#define NCP 16384              // padded cells per batch (24^3 = 13824)
#define GMIN (-6.0f)
#define CS 0.5f
#define INVCS 2.0f
#define FINF 3.4e38f
#define QPT 32                 // queries per tile
#define BUF 1536               // LDS staging slots (float4 + int idx)
#define NST 16                 // slot-streams (eval lanes per staged point)

__device__ __forceinline__ int cellc(float v) {
    int c = (int)((v - GMIN) * INVCS);
    return min(max(c, 0), GS - 1);
}

// branchless sorted top-3 update (R5-proven). Strict '<': incumbent wins ties.
#define INS3(d, idx, E0, E1, E2, I0, I1, I2) do {                     \
    bool c0 = (d) < E0, c1 = (d) < E1, c2 = (d) < E2;                 \
    float n1_ = __builtin_amdgcn_fmed3f(E0, E1, (d));                 \
    float n2_ = __builtin_amdgcn_fmed3f(E1, E2, (d));                 \
    I2 = c1 ? I1 : (c2 ? (idx) : I2);                                 \
    I1 = c0 ? I0 : (c1 ? (idx) : I1);                                 \
    I0 = c0 ? (idx) : I0;                                             \
    E0 = fminf(E0, (d)); E1 = n1_; E2 = n2_;                          \
} while (0)

// shared IDW epilogue: id* are global sorted candidate indices
__device__ __forceinline__ void idw_write(
    float qx, float qy, float qz, int n0, int n1, int n2,
    const float4* __restrict__ ckey, const float4* __restrict__ cflow,
    float* __restrict__ out, int b, int origj)
{
    float wsum = 0.f, f2x = 0.f, f2y = 0.f, f2z = 0.f;
    int idxs[3] = { n0, n1, n2 };
    #pragma unroll
    for (int k = 0; k < 3; ++k) {
        int id = idxs[k];
        float4 c = ckey[id];
        float cx = -0.5f * c.x, cy = -0.5f * c.y, cz = -0.5f * c.z;  // exact
        float dx = cx - qx, dy = cy - qy, dz = cz - qz;
        float dist = sqrtf(fmaf(dx, dx, fmaf(dy, dy, dz * dz)));
        dist = fmaxf(dist, 1e-10f);
        float w = 1.0f / dist;
        wsum += w;
        float4 fl = cflow[id];
        f2x = fmaf(w, fl.x, f2x);
        f2y = fmaf(w, fl.y, f2y);
        f2z = fmaf(w, fl.z, f2z);
    }
    float r = 1.0f / wsum;
    float* ob = out + b * 3 * NPTS;
    ob[origj]            = qx - f2x * r;
    ob[NPTS + origj]     = qy - f2y * r;
    ob[2 * NPTS + origj] = qz - f2z * r;
}

// ---------------------------------------------------------------------------
// K1: fused counting sort — bin + scan + scatter in ONE kernel (R17-proven).
// Grid = 8 blocks x 1024 thr: block (b*2+kind); kind 0 = candidates,
// kind 1 = queries. 16384-cell histogram in 64 KB LDS; LDS-atomic bin ->
// shfl scan -> cstart write (padding cells carry batch total => sentinel
// free) -> LDS cursors -> LDS-atomic scatter. Query blocks zero fbcnt[b].
// ---------------------------------------------------------------------------
__global__ __launch_bounds__(1024) void sort_all(
    const float* __restrict__ xyz1, const float* __restrict__ xyz2,
    const float* __restrict__ flow1,
    float4* __restrict__ ckey, float4* __restrict__ cflow,
    float4* __restrict__ qpos, int* __restrict__ cstart, int* __restrict__ fbcnt)
{
    __shared__ int hist[NCP];            // 64 KB
    __shared__ int wsum[16], wpre[16];

    int blk = blockIdx.x;                // b*2 + kind
    int b = blk >> 1, kind = blk & 1;
    int t = (int)threadIdx.x;
    int lane = t & 63, wid = t >> 6;

    #pragma unroll
    for (int i = t; i < NCP; i += 1024) hist[i] = 0;
    __syncthreads();

    const float* X = (kind == 0) ? (xyz1 + b * 3 * NPTS) : (xyz2 + b * 3 * NPTS);
    const float* F = flow1 + b * 3 * NPTS;

    #pragma unroll
    for (int i = 0; i < 8; ++i) {
        int n = t + i * 1024;
        float wx = X[n], wy = X[NPTS + n], wz = X[2 * NPTS + n];
        if (kind == 0) { wx += F[n]; wy += F[NPTS + n]; wz += F[2 * NPTS + n]; }
        int loc = (cellc(wz) * GS + cellc(wy)) * GS + cellc(wx);
        atomicAdd(&hist[loc], 1);
    }
    __syncthreads();

    int base = t * 16;
    int local[16];
    int s = 0;
    #pragma unroll
    for (int i = 0; i < 16; ++i) { local[i] = s; s += hist[base + i]; }
    int incl = s;
    #pragma unroll
    for (int o = 1; o < 64; o <<= 1) {
        int n = __shfl_up(incl, o);
        if (lane >= o) incl += n;
    }
    if (lane == 63) wsum[wid] = incl;
    __syncthreads();
    if (t < 16) {
        int wv = wsum[t];
        int wincl = wv;
        #pragma unroll
        for (int o = 1; o < 16; o <<= 1) {
            int n = __shfl_up(wincl, o);
            if (t >= o) wincl += n;
        }
        wpre[t] = wincl - wv;
    }
    __syncthreads();
    int off = b * NPTS + wpre[wid] + (incl - s);     // global exclusive base
    #pragma unroll
    for (int i = 0; i < 16; ++i) {
        int v = off + local[i];
        if (kind == 0) cstart[b * NCP + base + i] = v;
        local[i] = v;
    }
    __syncthreads();
    #pragma unroll
    for (int i = 0; i < 16; ++i) hist[base + i] = local[i];
    if (kind == 1 && t == 0) fbcnt[b] = 0;
    __syncthreads();

    #pragma unroll
    for (int i = 0; i < 8; ++i) {
        int n = t + i * 1024;
        float ax = X[n], ay = X[NPTS + n], az = X[2 * NPTS + n];
        if (kind == 0) {
            float fx = F[n], fy = F[NPTS + n], fz = F[2 * NPTS + n];
            float wx = ax + fx, wy = ay + fy, wz = az + fz;
            int loc = (cellc(wz) * GS + cellc(wy)) * GS + cellc(wx);
            int pos = atomicAdd(&hist[loc], 1);
            float nrm = fmaf(wx, wx, fmaf(wy, wy, wz * wz));
            ckey[pos]  = make_float4(-2.0f*wx, -2.0f*wy, -2.0f*wz, nrm);
            cflow[pos] = make_float4(fx, fy, fz, 0.0f);
        } else {
            int loc = (cellc(az) * GS + cellc(ay)) * GS + cellc(ax);
            int pos = atomicAdd(&hist[loc], 1);
            qpos[pos] = make_float4(ax, ay, az, __int_as_float(n));
        }
    }
}

// ---------------------------------------------------------------------------
// K2: main pass — R16's accumulate-then-stream (byte-identical, proven 54us).
// Block = 512 thr = 32 sorted queries x 16 slot-streams.
// ---------------------------------------------------------------------------
#define STREAM(lim) do {                                              \
    for (int i_ = so; i_ < (lim); i_ += NST) {                        \
        float4 c_ = sc[i_];                                           \
        int kk_ = sidx[i_];                                           \
        float d_ = fmaf(c_.x, qx, fmaf(c_.y, qy, fmaf(c_.z, qz, c_.w))); \
        INS3(d_, kk_, e0, e1, e2, i0, i1, i2);                        \
    }                                                                 \
} while (0)

__global__ __launch_bounds__(512) void knn_tile(
    const float4* __restrict__ qpos, const float4* __restrict__ ckey,
    const float4* __restrict__ cflow, const int* __restrict__ cstart,
    int* __restrict__ fbcnt, int* __restrict__ fblist, float* __restrict__ out)
{
    __shared__ float4 sc[BUF];
    __shared__ int    sidx[BUF];
    float* md = (float*)&sc[0];                       // [16][32][3], aliases sc
    int*   mi = (int*)((char*)&sc[0] + 6144);         // next 6144 B of sc

    int tile = blockIdx.x;               // BATCH*256
    int b = tile >> 8, ti = tile & 255;
    int t = (int)threadIdx.x;
    int lane = t & 63, so = t >> 5, l = t & 31, w = t >> 6;
    int qbase = b * NPTS + ti * QPT;

    float4 qp = qpos[qbase + l];
    float qx = qp.x, qy = qp.y, qz = qp.z;
    int origj = __float_as_int(qp.w);
    float qn = fmaf(qx, qx, fmaf(qy, qy, qz * qz));
    int hx = cellc(qx), hy = cellc(qy), hz = cellc(qz);

    int zmn = hz, zmx = hz;
    #pragma unroll
    for (int o = 32; o >= 1; o >>= 1) {
        zmn = min(zmn, __shfl_xor(zmn, o));
        zmx = max(zmx, __shfl_xor(zmx, o));
    }
    int loz = max(zmn - 1, 0), hiz = min(zmx + 1, GS - 1);

    float e0 = FINF, e1 = FINF, e2 = FINF;
    int   i0 = 0, i1 = 0, i2 = 0;
    int bufofs = 0;
    int bN = b * NCP;

    for (int z = loz; z <= hiz; ++z) {
        bool act = (hz - z <= 1) && (z - hz <= 1);
        int ymn = act ? hy : 1000, ymx = act ? hy : -1000;
        int xmn = act ? hx : 1000, xmx = act ? hx : -1000;
        #pragma unroll
        for (int o = 32; o >= 1; o >>= 1) {
            ymn = min(ymn, __shfl_xor(ymn, o));
            ymx = max(ymx, __shfl_xor(ymx, o));
            xmn = min(xmn, __shfl_xor(xmn, o));
            xmx = max(xmx, __shfl_xor(xmx, o));
        }
        if (ymn == 1000) continue;                 // no query needs this slab
        int ylo = max(ymn - 1, 0), yhi = min(ymx + 1, GS - 1);
        int xlo = max(xmn - 1, 0), xhi = min(xmx + 1, GS - 1);
        int nrows = yhi - ylo + 1;                 // <= 24 < 64

        int strt = 0, rlen = 0;
        if (lane < nrows) {
            int rb = bN + (z * GS + (ylo + lane)) * GS;
            strt = cstart[rb + xlo];
            rlen = cstart[rb + xhi + 1] - strt;
        }
        int incl = rlen;
        #pragma unroll
        for (int o = 1; o < 64; o <<= 1) {
            int n = __shfl_up(incl, o);
            if (lane >= o) incl += n;
        }
        int excl = incl - rlen;
        int T = __shfl(incl, 63);

        int copied = 0;
        while (copied < T) {                       // uniform loop
            int cnt = min(T - copied, BUF - bufofs);
            for (int r = w; r < nrows; r += 8) {   // wave w copies rows w,w+8,..
                int rofs = __shfl(excl, r);
                int rst  = __shfl(strt, r);
                int rln  = __shfl(rlen, r);
                int lo = max(rofs, copied), hi = min(rofs + rln, copied + cnt);
                for (int i = lo + lane; i < hi; i += 64) {
                    int dst = bufofs + (i - copied);
                    int src = rst + (i - rofs);
                    sc[dst] = ckey[src];
                    sidx[dst] = src;
                }
            }
            bufofs += cnt; copied += cnt;
            if (bufofs == BUF) {                   // uniform
                __syncthreads();
                STREAM(BUF);
                __syncthreads();
                bufofs = 0;
            }
        }
    }
    __syncthreads();
    if (bufofs > 0) STREAM(bufofs);                // uniform
    __syncthreads();                               // sc reused as md/mi below

    md[(so * 32 + l) * 3 + 0] = e0;  mi[(so * 32 + l) * 3 + 0] = i0;
    md[(so * 32 + l) * 3 + 1] = e1;  mi[(so * 32 + l) * 3 + 1] = i1;
    md[(so * 32 + l) * 3 + 2] = e2;  mi[(so * 32 + l) * 3 + 2] = i2;
    __syncthreads();

    if (t < QPT) {
        float m0 = FINF, m1 = FINF, m2 = FINF;
        int   n0 = 0, n1 = 0, n2 = 0;
        #pragma unroll
        for (int ss = 0; ss < NST; ++ss) {
            int bx = (ss * 32 + t) * 3;
            INS3(md[bx],     mi[bx],     m0, m1, m2, n0, n1, n2);
            INS3(md[bx + 1], mi[bx + 1], m0, m1, m2, n0, n1, n2);
            INS3(md[bx + 2], mi[bx + 2], m0, m1, m2, n0, n1, n2);
        }
        // per-query margin: distance to own +-1-cell-box faces (grid-edge skipped)
        float mg = FINF;
        if (hx > 1)      mg = fminf(mg, qx - (GMIN + (hx - 1) * CS));
        if (hx < GS - 2) mg = fminf(mg, (GMIN + (hx + 2) * CS) - qx);
        if (hy > 1)      mg = fminf(mg, qy - (GMIN + (hy - 1) * CS));
        if (hy < GS - 2) mg = fminf(mg, (GMIN + (hy + 2) * CS) - qy);
        if (hz > 1)      mg = fminf(mg, qz - (GMIN + (hz - 1) * CS));
        if (hz < GS - 2) mg = fminf(mg, (GMIN + (hz + 2) * CS) - qz);
        if (m2 + qn <= mg * mg) {
            idw_write(qx, qy, qz, n0, n1, n2, ckey, cflow, out, b, origj);
        } else {
            int p = atomicAdd(&fbcnt[b], 1);
            fblist[b * NPTS + p] = ti * QPT + t;   // batch-local sorted position
        }
    }
}

// ---------------------------------------------------------------------------
// K3: fb_box — grid-accelerated fallback. One wave per fallback query
// (strided over 1024 blocks). Expanding box S=2,4,8,...: lanes parallelize
// over the box's cells (per-lane cstart loads + point gathers -> latency
// pipelines), butterfly merge (symmetric -> all lanes converge), then the
// same exact margin test as knn_tile with the +-S box (grid-edge faces
// skipped; clamped points lie beyond the face plane -> unscanned => dist
// >= mg). Box covering the grid => mg = FINF => guaranteed termination.
// Top-3 state reset each round (no duplicate-insert corruption).
// ---------------------------------------------------------------------------
__global__ __launch_bounds__(256) void fb_box(
    const float4* __restrict__ qpos, const float4* __restrict__ ckey,
    const float4* __restrict__ cflow, const int* __restrict__ fbcnt,
    const int* __restrict__ fblist, const int* __restrict__ cstart,
    float* __restrict__ out)
{
    int blk = blockIdx.x;                 // 1024 = BATCH * 256
    int b = blk >> 8, grp = blk & 255;
    int t = (int)threadIdx.x;
    int w = t >> 6, ln = t & 63;
    int cnt = fbcnt[b];
    int bN = b * NCP;

    for (int idx = grp * 4 + w; idx < cnt; idx += 1024) {   // wave-uniform
        int js = fblist[b * NPTS + idx];
        float4 qp = qpos[b * NPTS + js];
        float qx = qp.x, qy = qp.y, qz = qp.z;
        int origj = __float_as_int(qp.w);
        float qn = fmaf(qx, qx, fmaf(qy, qy, qz * qz));
        int hx = cellc(qx), hy = cellc(qy), hz = cellc(qz);

        for (int S = 2; ; S <<= 1) {
            int lox = max(hx - S, 0), hix = min(hx + S, GS - 1);
            int loy = max(hy - S, 0), hiy = min(hy + S, GS - 1);
            int loz = max(hz - S, 0), hiz = min(hz + S, GS - 1);
            int nx = hix - lox + 1, ny = hiy - loy + 1, nz = hiz - loz + 1;
            int nxy = nx * ny;
            int total = nxy * nz;

            float e0 = FINF, e1 = FINF, e2 = FINF;
            int   i0 = 0, i1 = 0, i2 = 0;
            for (int c = ln; c < total; c += 64) {
                int dz = c / nxy;  int rem = c - dz * nxy;
                int dy = rem / nx; int dx = rem - dy * nx;
                int gc = bN + ((loz + dz) * GS + (loy + dy)) * GS + (lox + dx);
                int st = cstart[gc], en = cstart[gc + 1];
                for (int k = st; k < en; ++k) {
                    float4 cc = ckey[k];
                    float d = fmaf(cc.x, qx, fmaf(cc.y, qy, fmaf(cc.z, qz, cc.w)));
                    INS3(d, k, e0, e1, e2, i0, i1, i2);
                }
            }
            // butterfly merge (all lanes converge to the same top-3)
            #pragma unroll
            for (int o = 1; o < 64; o <<= 1) {
                float r0 = __shfl_xor(e0, o), r1 = __shfl_xor(e1, o), r2 = __shfl_xor(e2, o);
                int   s0 = __shfl_xor(i0, o), s1 = __shfl_xor(i1, o), s2 = __shfl_xor(i2, o);
                INS3(r0, s0, e0, e1, e2, i0, i1, i2);
                INS3(r1, s1, e0, e1, e2, i0, i1, i2);
                INS3(r2, s2, e0, e1, e2, i0, i1, i2);
            }
            // margin to +-S box faces (grid-edge faces skipped)
            float mg = FINF;
            if (lox > 0)      mg = fminf(mg, qx - (GMIN + lox * CS));
            if (hix < GS - 1) mg = fminf(mg, (GMIN + (hix + 1) * CS) - qx);
            if (loy > 0)      mg = fminf(mg, qy - (GMIN + loy * CS));
            if (hiy < GS - 1) mg = fminf(mg, (GMIN + (hiy + 1) * CS) - qy);
            if (loz > 0)      mg = fminf(mg, qz - (GMIN + loz * CS));
            if (hiz < GS - 1) mg = fminf(mg, (GMIN + (hiz + 1) * CS) - qz);
            if (e2 + qn <= mg * mg) {              // wave-uniform (merged state)
                if (ln == 0)
                    idw_write(qx, qy, qz, i0, i1, i2, ckey, cflow, out, b, origj);
                break;
            }
        }
    }
}

// ---------------------------------------------------------------------------
// Launcher. 3 dispatches. Workspace ~1.9 MB.
// ---------------------------------------------------------------------------
extern "C" void kernel_launch(void* const* d_in, const int* in_sizes, int n_in,
                              void* d_out, int out_size, void* d_ws, size_t ws_size,
                              hipStream_t stream)
{
    const float* xyz1  = (const float*)d_in[0];
    const float* xyz2  = (const float*)d_in[1];
    const float* flow1 = (const float*)d_in[2];
    float* out = (float*)d_out;

    char* p = (char*)d_ws;
    float4* ckey   = (float4*)p;  p += (size_t)BATCH * NPTS * 16;
    float4* cflow  = (float4*)p;  p += (size_t)BATCH * NPTS * 16;
    float4* qpos   = (float4*)p;  p += (size_t)BATCH * NPTS * 16;
    int*    cstart = (int*)p;     p += (size_t)BATCH * NCP * 4;
    int*    fbcnt  = (int*)p;     p += 16;
    int*    fblist = (int*)p;

    sort_all<<<2 * BATCH, 1024, 0, stream>>>(xyz1, xyz2, flow1, ckey, cflow,
                                             qpos, cstart, fbcnt);
    knn_tile<<<BATCH * (NPTS / QPT), 512, 0, stream>>>(qpos, ckey, cflow,
                                                       cstart, fbcnt, fblist, out);
    fb_box  <<<BATCH * 256, 256, 0, stream>>>(qpos, ckey, cflow, fbcnt, fblist,
                                              cstart, out);
}

// Round 19
// 116.036 us; speedup vs baseline: 1.0092x; 1.0092x over previous
//
#include <hip/hip_runtime.h>
#include <math.h>

#define BATCH 4
#define NPTS 8192
#define GS 24                  // 24^3 cells of 0.5 over [-6,6]^3
#define NCP 16384              // padded cells per batch (24^3 = 13824)
#define GMIN (-6.0f)
#define CS 0.5f
#define INVCS 2.0f
#define FINF 3.4e38f
#define QPT 32                 // queries per tile
#define BUF 1536               // LDS staging slots (float4 + int idx)
#define NST 16                 // slot-streams (eval lanes per staged point)

__device__ __forceinline__ int cellc(float v) {
    int c = (int)((v - GMIN) * INVCS);
    return min(max(c, 0), GS - 1);
}
__device__ __forceinline__ int qc16(float v) {   // coarse 16-bin coord
    int c = (int)((v - GMIN) * (16.0f / 12.0f));
    return min(max(c, 0), 15);
}
__device__ __forceinline__ int mort4(int x) {    // spread 4 bits to every 3rd pos
    return (x & 1) | ((x & 2) << 2) | ((x & 4) << 4) | ((x & 8) << 6);
}

// branchless sorted top-3 update (R5-proven). Strict '<': incumbent wins ties.
#define INS3(d, idx, E0, E1, E2, I0, I1, I2) do {                     \
    bool c0 = (d) < E0, c1 = (d) < E1, c2 = (d) < E2;                 \
    float n1_ = __builtin_amdgcn_fmed3f(E0, E1, (d));                 \
    float n2_ = __builtin_amdgcn_fmed3f(E1, E2, (d));                 \
    I2 = c1 ? I1 : (c2 ? (idx) : I2);                                 \
    I1 = c0 ? I0 : (c1 ? (idx) : I1);                                 \
    I0 = c0 ? (idx) : I0;                                             \
    E0 = fminf(E0, (d)); E1 = n1_; E2 = n2_;                          \
} while (0)

// shared IDW epilogue: id* are global sorted candidate indices
__device__ __forceinline__ void idw_write(
    float qx, float qy, float qz, int n0, int n1, int n2,
    const float4* __restrict__ ckey, const float4* __restrict__ cflow,
    float* __restrict__ out, int b, int origj)
{
    float wsum = 0.f, f2x = 0.f, f2y = 0.f, f2z = 0.f;
    int idxs[3] = { n0, n1, n2 };
    #pragma unroll
    for (int k = 0; k < 3; ++k) {
        int id = idxs[k];
        float4 c = ckey[id];
        float cx = -0.5f * c.x, cy = -0.5f * c.y, cz = -0.5f * c.z;  // exact
        float dx = cx - qx, dy = cy - qy, dz = cz - qz;
        float dist = sqrtf(fmaf(dx, dx, fmaf(dy, dy, dz * dz)));
        dist = fmaxf(dist, 1e-10f);
        float w = 1.0f / dist;
        wsum += w;
        float4 fl = cflow[id];
        f2x = fmaf(w, fl.x, f2x);
        f2y = fmaf(w, fl.y, f2y);
        f2z = fmaf(w, fl.z, f2z);
    }
    float r = 1.0f / wsum;
    float* ob = out + b * 3 * NPTS;
    ob[origj]            = qx - f2x * r;
    ob[NPTS + origj]     = qy - f2y * r;
    ob[2 * NPTS + origj] = qz - f2z * r;
}

// ---------------------------------------------------------------------------
// K1: fused counting sort — bin + scan + scatter in ONE kernel (R17-proven).
// Grid = 8 blocks x 1024 thr: block (b*2+kind); kind 0 = candidates (fine
// 24^3 cells), kind 1 = queries (MORTON 16^3 bins -> compact query tiles).
// 16384-entry histogram in 64 KB LDS; LDS-atomic bin -> shfl scan -> cstart
// write (padding cells carry batch total => sentinel free) -> LDS cursors ->
// LDS-atomic scatter. Query blocks zero fbcnt[b].
// ---------------------------------------------------------------------------
__global__ __launch_bounds__(1024) void sort_all(
    const float* __restrict__ xyz1, const float* __restrict__ xyz2,
    const float* __restrict__ flow1,
    float4* __restrict__ ckey, float4* __restrict__ cflow,
    float4* __restrict__ qpos, int* __restrict__ cstart, int* __restrict__ fbcnt)
{
    __shared__ int hist[NCP];            // 64 KB
    __shared__ int wsum[16], wpre[16];

    int blk = blockIdx.x;                // b*2 + kind
    int b = blk >> 1, kind = blk & 1;
    int t = (int)threadIdx.x;
    int lane = t & 63, wid = t >> 6;

    #pragma unroll
    for (int i = t; i < NCP; i += 1024) hist[i] = 0;
    __syncthreads();

    const float* X = (kind == 0) ? (xyz1 + b * 3 * NPTS) : (xyz2 + b * 3 * NPTS);
    const float* F = flow1 + b * 3 * NPTS;

    #pragma unroll
    for (int i = 0; i < 8; ++i) {
        int n = t + i * 1024;
        float wx = X[n], wy = X[NPTS + n], wz = X[2 * NPTS + n];
        int loc;
        if (kind == 0) {
            wx += F[n]; wy += F[NPTS + n]; wz += F[2 * NPTS + n];
            loc = (cellc(wz) * GS + cellc(wy)) * GS + cellc(wx);
        } else {
            loc = mort4(qc16(wx)) | (mort4(qc16(wy)) << 1) | (mort4(qc16(wz)) << 2);
        }
        atomicAdd(&hist[loc], 1);
    }
    __syncthreads();

    int base = t * 16;
    int local[16];
    int s = 0;
    #pragma unroll
    for (int i = 0; i < 16; ++i) { local[i] = s; s += hist[base + i]; }
    int incl = s;
    #pragma unroll
    for (int o = 1; o < 64; o <<= 1) {
        int n = __shfl_up(incl, o);
        if (lane >= o) incl += n;
    }
    if (lane == 63) wsum[wid] = incl;
    __syncthreads();
    if (t < 16) {
        int wv = wsum[t];
        int wincl = wv;
        #pragma unroll
        for (int o = 1; o < 16; o <<= 1) {
            int n = __shfl_up(wincl, o);
            if (t >= o) wincl += n;
        }
        wpre[t] = wincl - wv;
    }
    __syncthreads();
    int off = b * NPTS + wpre[wid] + (incl - s);     // global exclusive base
    #pragma unroll
    for (int i = 0; i < 16; ++i) {
        int v = off + local[i];
        if (kind == 0) cstart[b * NCP + base + i] = v;
        local[i] = v;
    }
    __syncthreads();
    #pragma unroll
    for (int i = 0; i < 16; ++i) hist[base + i] = local[i];
    if (kind == 1 && t == 0) fbcnt[b] = 0;
    __syncthreads();

    #pragma unroll
    for (int i = 0; i < 8; ++i) {
        int n = t + i * 1024;
        float ax = X[n], ay = X[NPTS + n], az = X[2 * NPTS + n];
        if (kind == 0) {
            float fx = F[n], fy = F[NPTS + n], fz = F[2 * NPTS + n];
            float wx = ax + fx, wy = ay + fy, wz = az + fz;
            int loc = (cellc(wz) * GS + cellc(wy)) * GS + cellc(wx);
            int pos = atomicAdd(&hist[loc], 1);
            float nrm = fmaf(wx, wx, fmaf(wy, wy, wz * wz));
            ckey[pos]  = make_float4(-2.0f*wx, -2.0f*wy, -2.0f*wz, nrm);
            cflow[pos] = make_float4(fx, fy, fz, 0.0f);
        } else {
            int loc = mort4(qc16(ax)) | (mort4(qc16(ay)) << 1) | (mort4(qc16(az)) << 2);
            int pos = atomicAdd(&hist[loc], 1);
            qpos[pos] = make_float4(ax, ay, az, __int_as_float(n));
        }
    }
}

// ---------------------------------------------------------------------------
// K2: main pass — R16's accumulate-then-stream (byte-identical, proven 54us;
// only the ORDER of qpos entries changed -> tighter tile bboxes).
// Block = 512 thr = 32 Morton-sorted queries x 16 slot-streams.
// ---------------------------------------------------------------------------
#define STREAM(lim) do {                                              \
    for (int i_ = so; i_ < (lim); i_ += NST) {                        \
        float4 c_ = sc[i_];                                           \
        int kk_ = sidx[i_];                                           \
        float d_ = fmaf(c_.x, qx, fmaf(c_.y, qy, fmaf(c_.z, qz, c_.w))); \
        INS3(d_, kk_, e0, e1, e2, i0, i1, i2);                        \
    }                                                                 \
} while (0)

__global__ __launch_bounds__(512) void knn_tile(
    const float4* __restrict__ qpos, const float4* __restrict__ ckey,
    const float4* __restrict__ cflow, const int* __restrict__ cstart,
    int* __restrict__ fbcnt, int* __restrict__ fblist, float* __restrict__ out)
{
    __shared__ float4 sc[BUF];
    __shared__ int    sidx[BUF];
    float* md = (float*)&sc[0];                       // [16][32][3], aliases sc
    int*   mi = (int*)((char*)&sc[0] + 6144);         // next 6144 B of sc

    int tile = blockIdx.x;               // BATCH*256
    int b = tile >> 8, ti = tile & 255;
    int t = (int)threadIdx.x;
    int lane = t & 63, so = t >> 5, l = t & 31, w = t >> 6;
    int qbase = b * NPTS + ti * QPT;

    float4 qp = qpos[qbase + l];
    float qx = qp.x, qy = qp.y, qz = qp.z;
    int origj = __float_as_int(qp.w);
    float qn = fmaf(qx, qx, fmaf(qy, qy, qz * qz));
    int hx = cellc(qx), hy = cellc(qy), hz = cellc(qz);

    int zmn = hz, zmx = hz;
    #pragma unroll
    for (int o = 32; o >= 1; o >>= 1) {
        zmn = min(zmn, __shfl_xor(zmn, o));
        zmx = max(zmx, __shfl_xor(zmx, o));
    }
    int loz = max(zmn - 1, 0), hiz = min(zmx + 1, GS - 1);

    float e0 = FINF, e1 = FINF, e2 = FINF;
    int   i0 = 0, i1 = 0, i2 = 0;
    int bufofs = 0;
    int bN = b * NCP;

    for (int z = loz; z <= hiz; ++z) {
        bool act = (hz - z <= 1) && (z - hz <= 1);
        int ymn = act ? hy : 1000, ymx = act ? hy : -1000;
        int xmn = act ? hx : 1000, xmx = act ? hx : -1000;
        #pragma unroll
        for (int o = 32; o >= 1; o >>= 1) {
            ymn = min(ymn, __shfl_xor(ymn, o));
            ymx = max(ymx, __shfl_xor(ymx, o));
            xmn = min(xmn, __shfl_xor(xmn, o));
            xmx = max(xmx, __shfl_xor(xmx, o));
        }
        if (ymn == 1000) continue;                 // no query needs this slab
        int ylo = max(ymn - 1, 0), yhi = min(ymx + 1, GS - 1);
        int xlo = max(xmn - 1, 0), xhi = min(xmx + 1, GS - 1);
        int nrows = yhi - ylo + 1;                 // <= 24 < 64

        int strt = 0, rlen = 0;
        if (lane < nrows) {
            int rb = bN + (z * GS + (ylo + lane)) * GS;
            strt = cstart[rb + xlo];
            rlen = cstart[rb + xhi + 1] - strt;
        }
        int incl = rlen;
        #pragma unroll
        for (int o = 1; o < 64; o <<= 1) {
            int n = __shfl_up(incl, o);
            if (lane >= o) incl += n;
        }
        int excl = incl - rlen;
        int T = __shfl(incl, 63);

        int copied = 0;
        while (copied < T) {                       // uniform loop
            int cnt = min(T - copied, BUF - bufofs);
            for (int r = w; r < nrows; r += 8) {   // wave w copies rows w,w+8,..
                int rofs = __shfl(excl, r);
                int rst  = __shfl(strt, r);
                int rln  = __shfl(rlen, r);
                int lo = max(rofs, copied), hi = min(rofs + rln, copied + cnt);
                for (int i = lo + lane; i < hi; i += 64) {
                    int dst = bufofs + (i - copied);
                    int src = rst + (i - rofs);
                    sc[dst] = ckey[src];
                    sidx[dst] = src;
                }
            }
            bufofs += cnt; copied += cnt;
            if (bufofs == BUF) {                   // uniform
                __syncthreads();
                STREAM(BUF);
                __syncthreads();
                bufofs = 0;
            }
        }
    }
    __syncthreads();
    if (bufofs > 0) STREAM(bufofs);                // uniform
    __syncthreads();                               // sc reused as md/mi below

    md[(so * 32 + l) * 3 + 0] = e0;  mi[(so * 32 + l) * 3 + 0] = i0;
    md[(so * 32 + l) * 3 + 1] = e1;  mi[(so * 32 + l) * 3 + 1] = i1;
    md[(so * 32 + l) * 3 + 2] = e2;  mi[(so * 32 + l) * 3 + 2] = i2;
    __syncthreads();

    if (t < QPT) {
        float m0 = FINF, m1 = FINF, m2 = FINF;
        int   n0 = 0, n1 = 0, n2 = 0;
        #pragma unroll
        for (int ss = 0; ss < NST; ++ss) {
            int bx = (ss * 32 + t) * 3;
            INS3(md[bx],     mi[bx],     m0, m1, m2, n0, n1, n2);
            INS3(md[bx + 1], mi[bx + 1], m0, m1, m2, n0, n1, n2);
            INS3(md[bx + 2], mi[bx + 2], m0, m1, m2, n0, n1, n2);
        }
        // per-query margin: distance to own +-1-cell-box faces (grid-edge skipped)
        float mg = FINF;
        if (hx > 1)      mg = fminf(mg, qx - (GMIN + (hx - 1) * CS));
        if (hx < GS - 2) mg = fminf(mg, (GMIN + (hx + 2) * CS) - qx);
        if (hy > 1)      mg = fminf(mg, qy - (GMIN + (hy - 1) * CS));
        if (hy < GS - 2) mg = fminf(mg, (GMIN + (hy + 2) * CS) - qy);
        if (hz > 1)      mg = fminf(mg, qz - (GMIN + (hz - 1) * CS));
        if (hz < GS - 2) mg = fminf(mg, (GMIN + (hz + 2) * CS) - qz);
        if (m2 + qn <= mg * mg) {
            idw_write(qx, qy, qz, n0, n1, n2, ckey, cflow, out, b, origj);
        } else {
            int p = atomicAdd(&fbcnt[b], 1);
            fblist[b * NPTS + p] = ti * QPT + t;   // batch-local sorted position
        }
    }
}

// ---------------------------------------------------------------------------
// K3: wave-per-query fallback (R12/R17-proven), strided grid (1024 blocks).
// Lane ln scans candidates ln, ln+64, ... (coalesced vector loads),
// butterfly shfl merge, lane 0 writes.
// ---------------------------------------------------------------------------
__global__ __launch_bounds__(256) void fb_wave(
    const float4* __restrict__ qpos, const float4* __restrict__ ckey,
    const float4* __restrict__ cflow, const int* __restrict__ fbcnt,
    const int* __restrict__ fblist, float* __restrict__ out)
{
    int blk = blockIdx.x;                 // 1024 = BATCH * 256
    int b = blk >> 8, grp = blk & 255;
    int t = (int)threadIdx.x;
    int w = t >> 6, ln = t & 63;
    int cnt = fbcnt[b];

    for (int idx = grp * 4 + w; idx < cnt; idx += 1024) {   // wave-uniform
        int js = fblist[b * NPTS + idx];
        float4 qp = qpos[b * NPTS + js];
        float qx = qp.x, qy = qp.y, qz = qp.z;
        int origj = __float_as_int(qp.w);

        const float4* src = ckey + b * NPTS;

        float e0 = FINF, e1 = FINF, e2 = FINF;
        int   i0 = 0, i1 = 0, i2 = 0;
        #pragma unroll 4
        for (int k = ln; k < NPTS; k += 64) {
            float4 c = src[k];
            float d = fmaf(c.x, qx, fmaf(c.y, qy, fmaf(c.z, qz, c.w)));
            INS3(d, k, e0, e1, e2, i0, i1, i2);
        }
        #pragma unroll
        for (int o = 1; o < 64; o <<= 1) {
            float r0 = __shfl_xor(e0, o), r1 = __shfl_xor(e1, o), r2 = __shfl_xor(e2, o);
            int   s0 = __shfl_xor(i0, o), s1 = __shfl_xor(i1, o), s2 = __shfl_xor(i2, o);
            INS3(r0, s0, e0, e1, e2, i0, i1, i2);
            INS3(r1, s1, e0, e1, e2, i0, i1, i2);
            INS3(r2, s2, e0, e1, e2, i0, i1, i2);
        }
        if (ln == 0) {
            idw_write(qx, qy, qz, b * NPTS + i0, b * NPTS + i1, b * NPTS + i2,
                      ckey, cflow, out, b, origj);
        }
    }
}

// ---------------------------------------------------------------------------
// Launcher. 3 dispatches. Workspace ~1.9 MB.
// ---------------------------------------------------------------------------
extern "C" void kernel_launch(void* const* d_in, const int* in_sizes, int n_in,
                              void* d_out, int out_size, void* d_ws, size_t ws_size,
                              hipStream_t stream)
{
    const float* xyz1  = (const float*)d_in[0];
    const float* xyz2  = (const float*)d_in[1];
    const float* flow1 = (const float*)d_in[2];
    float* out = (float*)d_out;

    char* p = (char*)d_ws;
    float4* ckey   = (float4*)p;  p += (size_t)BATCH * NPTS * 16;
    float4* cflow  = (float4*)p;  p += (size_t)BATCH * NPTS * 16;
    float4* qpos   = (float4*)p;  p += (size_t)BATCH * NPTS * 16;
    int*    cstart = (int*)p;     p += (size_t)BATCH * NCP * 4;
    int*    fbcnt  = (int*)p;     p += 16;
    int*    fblist = (int*)p;

    sort_all<<<2 * BATCH, 1024, 0, stream>>>(xyz1, xyz2, flow1, ckey, cflow,
                                             qpos, cstart, fbcnt);
    knn_tile<<<BATCH * (NPTS / QPT), 512, 0, stream>>>(qpos, ckey, cflow,
                                                       cstart, fbcnt, fblist, out);
    fb_wave <<<BATCH * 256, 256, 0, stream>>>(qpos, ckey, cflow, fbcnt, fblist, out);
}

// Round 20
// 97.485 us; speedup vs baseline: 1.2013x; 1.1903x over previous
//
#include <hip/hip_runtime.h>
#include <math.h>

#define BATCH 4
#define NPTS 8192
#define GS 24                  // 24^3 cells of 0.5 over [-6,6]^3
#define NCP 16384              // padded cells per batch (24^3 = 13824)
#define GMIN (-6.0f)
#define CS 0.5f
#define INVCS 2.0f
#define FINF 3.4e38f
#define QPT 32                 // queries per tile
#define SEGSZ 768              // LDS staging slots per segment (x2 segments)
#define NST 16                 // slot-streams (eval lanes per staged point)

__device__ __forceinline__ int cellc(float v) {
    int c = (int)((v - GMIN) * INVCS);
    return min(max(c, 0), GS - 1);
}

// branchless sorted top-3 update (R5-proven). Strict '<': incumbent wins ties.
#define INS3(d, idx, E0, E1, E2, I0, I1, I2) do {                     \
    bool c0 = (d) < E0, c1 = (d) < E1, c2 = (d) < E2;                 \
    float n1_ = __builtin_amdgcn_fmed3f(E0, E1, (d));                 \
    float n2_ = __builtin_amdgcn_fmed3f(E1, E2, (d));                 \
    I2 = c1 ? I1 : (c2 ? (idx) : I2);                                 \
    I1 = c0 ? I0 : (c1 ? (idx) : I1);                                 \
    I0 = c0 ? (idx) : I0;                                             \
    E0 = fminf(E0, (d)); E1 = n1_; E2 = n2_;                          \
} while (0)

// shared IDW epilogue: id* are global sorted candidate indices
__device__ __forceinline__ void idw_write(
    float qx, float qy, float qz, int n0, int n1, int n2,
    const float4* __restrict__ ckey, const float4* __restrict__ cflow,
    float* __restrict__ out, int b, int origj)
{
    float wsum = 0.f, f2x = 0.f, f2y = 0.f, f2z = 0.f;
    int idxs[3] = { n0, n1, n2 };
    #pragma unroll
    for (int k = 0; k < 3; ++k) {
        int id = idxs[k];
        float4 c = ckey[id];
        float cx = -0.5f * c.x, cy = -0.5f * c.y, cz = -0.5f * c.z;  // exact
        float dx = cx - qx, dy = cy - qy, dz = cz - qz;
        float dist = sqrtf(fmaf(dx, dx, fmaf(dy, dy, dz * dz)));
        dist = fmaxf(dist, 1e-10f);
        float w = 1.0f / dist;
        wsum += w;
        float4 fl = cflow[id];
        f2x = fmaf(w, fl.x, f2x);
        f2y = fmaf(w, fl.y, f2y);
        f2z = fmaf(w, fl.z, f2z);
    }
    float r = 1.0f / wsum;
    float* ob = out + b * 3 * NPTS;
    ob[origj]            = qx - f2x * r;
    ob[NPTS + origj]     = qy - f2y * r;
    ob[2 * NPTS + origj] = qz - f2z * r;
}

// ---------------------------------------------------------------------------
// K1: fused counting sort — bin + scan + scatter in ONE kernel (R17-proven,
// raster cell order for BOTH candidates and queries).
// Grid = 8 blocks x 1024 thr: block (b*2+kind); kind 0 = candidates,
// kind 1 = queries. 16384-cell histogram in 64 KB LDS; LDS-atomic bin ->
// shfl scan -> cstart write (padding cells carry batch total => sentinel
// free) -> LDS cursors -> LDS-atomic scatter. Query blocks zero fbcnt[b].
// ---------------------------------------------------------------------------
__global__ __launch_bounds__(1024) void sort_all(
    const float* __restrict__ xyz1, const float* __restrict__ xyz2,
    const float* __restrict__ flow1,
    float4* __restrict__ ckey, float4* __restrict__ cflow,
    float4* __restrict__ qpos, int* __restrict__ cstart, int* __restrict__ fbcnt)
{
    __shared__ int hist[NCP];            // 64 KB
    __shared__ int wsum[16], wpre[16];

    int blk = blockIdx.x;                // b*2 + kind
    int b = blk >> 1, kind = blk & 1;
    int t = (int)threadIdx.x;
    int lane = t & 63, wid = t >> 6;

    #pragma unroll
    for (int i = t; i < NCP; i += 1024) hist[i] = 0;
    __syncthreads();

    const float* X = (kind == 0) ? (xyz1 + b * 3 * NPTS) : (xyz2 + b * 3 * NPTS);
    const float* F = flow1 + b * 3 * NPTS;

    #pragma unroll
    for (int i = 0; i < 8; ++i) {
        int n = t + i * 1024;
        float wx = X[n], wy = X[NPTS + n], wz = X[2 * NPTS + n];
        if (kind == 0) { wx += F[n]; wy += F[NPTS + n]; wz += F[2 * NPTS + n]; }
        int loc = (cellc(wz) * GS + cellc(wy)) * GS + cellc(wx);
        atomicAdd(&hist[loc], 1);
    }
    __syncthreads();

    int base = t * 16;
    int local[16];
    int s = 0;
    #pragma unroll
    for (int i = 0; i < 16; ++i) { local[i] = s; s += hist[base + i]; }
    int incl = s;
    #pragma unroll
    for (int o = 1; o < 64; o <<= 1) {
        int n = __shfl_up(incl, o);
        if (lane >= o) incl += n;
    }
    if (lane == 63) wsum[wid] = incl;
    __syncthreads();
    if (t < 16) {
        int wv = wsum[t];
        int wincl = wv;
        #pragma unroll
        for (int o = 1; o < 16; o <<= 1) {
            int n = __shfl_up(wincl, o);
            if (t >= o) wincl += n;
        }
        wpre[t] = wincl - wv;
    }
    __syncthreads();
    int off = b * NPTS + wpre[wid] + (incl - s);     // global exclusive base
    #pragma unroll
    for (int i = 0; i < 16; ++i) {
        int v = off + local[i];
        if (kind == 0) cstart[b * NCP + base + i] = v;
        local[i] = v;
    }
    __syncthreads();
    #pragma unroll
    for (int i = 0; i < 16; ++i) hist[base + i] = local[i];
    if (kind == 1 && t == 0) fbcnt[b] = 0;
    __syncthreads();

    #pragma unroll
    for (int i = 0; i < 8; ++i) {
        int n = t + i * 1024;
        float ax = X[n], ay = X[NPTS + n], az = X[2 * NPTS + n];
        if (kind == 0) {
            float fx = F[n], fy = F[NPTS + n], fz = F[2 * NPTS + n];
            float wx = ax + fx, wy = ay + fy, wz = az + fz;
            int loc = (cellc(wz) * GS + cellc(wy)) * GS + cellc(wx);
            int pos = atomicAdd(&hist[loc], 1);
            float nrm = fmaf(wx, wx, fmaf(wy, wy, wz * wz));
            ckey[pos]  = make_float4(-2.0f*wx, -2.0f*wy, -2.0f*wz, nrm);
            cflow[pos] = make_float4(fx, fy, fz, 0.0f);
        } else {
            int loc = (cellc(az) * GS + cellc(ay)) * GS + cellc(ax);
            int pos = atomicAdd(&hist[loc], 1);
            qpos[pos] = make_float4(ax, ay, az, __int_as_float(n));
        }
    }
}

// ---------------------------------------------------------------------------
// K2: main pass — accumulate-then-stream with DOUBLE-BUFFERED segments.
// Block = 512 thr = 32 raster-sorted queries (l = t&31) x 16 slot-streams.
// Two 768-slot LDS segments: per barrier window, fill segment f (global
// loads issued early, across slabs) THEN stream segment f^1 (filled in the
// previous window) -> copy latency hides under stream compute; ONE barrier
// per 768 points (was 2 per 1536, with copy latency fully exposed).
// Resolve via per-query +-1-cell-box margin (grid-edge faces skipped) ->
// exact. Unresolved -> compacted per-batch fallback list.
// ---------------------------------------------------------------------------
#define STREAM_SEG(sg, lim) do {                                      \
    for (int i_ = so; i_ < (lim); i_ += NST) {                        \
        float4 c_ = sc[sg][i_];                                       \
        int kk_ = sidx[sg][i_];                                       \
        float d_ = fmaf(c_.x, qx, fmaf(c_.y, qy, fmaf(c_.z, qz, c_.w))); \
        INS3(d_, kk_, e0, e1, e2, i0, i1, i2);                        \
    }                                                                 \
} while (0)

__global__ __launch_bounds__(512) void knn_tile(
    const float4* __restrict__ qpos, const float4* __restrict__ ckey,
    const float4* __restrict__ cflow, const int* __restrict__ cstart,
    int* __restrict__ fbcnt, int* __restrict__ fblist, float* __restrict__ out)
{
    __shared__ float4 sc[2][SEGSZ];      // 24576 B
    __shared__ int    sidx[2][SEGSZ];    //  6144 B
    float* md = (float*)&sc[0][0];       // [16][32][3] = 6144 B, aliases sc
    int*   mi = (int*)((char*)&sc[0][0] + 6144);   // next 6144 B

    int tile = blockIdx.x;               // BATCH*256
    int b = tile >> 8, ti = tile & 255;
    int t = (int)threadIdx.x;
    int lane = t & 63, so = t >> 5, l = t & 31, w = t >> 6;
    int qbase = b * NPTS + ti * QPT;

    float4 qp = qpos[qbase + l];
    float qx = qp.x, qy = qp.y, qz = qp.z;
    int origj = __float_as_int(qp.w);
    float qn = fmaf(qx, qx, fmaf(qy, qy, qz * qz));
    int hx = cellc(qx), hy = cellc(qy), hz = cellc(qz);

    int zmn = hz, zmx = hz;
    #pragma unroll
    for (int o = 32; o >= 1; o >>= 1) {
        zmn = min(zmn, __shfl_xor(zmn, o));
        zmx = max(zmx, __shfl_xor(zmx, o));
    }
    int loz = max(zmn - 1, 0), hiz = min(zmx + 1, GS - 1);

    float e0 = FINF, e1 = FINF, e2 = FINF;
    int   i0 = 0, i1 = 0, i2 = 0;
    int fseg = 0, fofs = 0;              // fill segment / offset
    int pend = -1;                       // pts in segment fseg^1 awaiting stream
    int bN = b * NCP;

    for (int z = loz; z <= hiz; ++z) {
        bool act = (hz - z <= 1) && (z - hz <= 1);
        int ymn = act ? hy : 1000, ymx = act ? hy : -1000;
        int xmn = act ? hx : 1000, xmx = act ? hx : -1000;
        #pragma unroll
        for (int o = 32; o >= 1; o >>= 1) {
            ymn = min(ymn, __shfl_xor(ymn, o));
            ymx = max(ymx, __shfl_xor(ymx, o));
            xmn = min(xmn, __shfl_xor(xmn, o));
            xmx = max(xmx, __shfl_xor(xmx, o));
        }
        if (ymn == 1000) continue;                 // no query needs this slab
        int ylo = max(ymn - 1, 0), yhi = min(ymx + 1, GS - 1);
        int xlo = max(xmn - 1, 0), xhi = min(xmx + 1, GS - 1);
        int nrows = yhi - ylo + 1;                 // <= 24 < 64

        int strt = 0, rlen = 0;
        if (lane < nrows) {
            int rb = bN + (z * GS + (ylo + lane)) * GS;
            strt = cstart[rb + xlo];
            rlen = cstart[rb + xhi + 1] - strt;
        }
        int incl = rlen;
        #pragma unroll
        for (int o = 1; o < 64; o <<= 1) {
            int n = __shfl_up(incl, o);
            if (lane >= o) incl += n;
        }
        int excl = incl - rlen;
        int T = __shfl(incl, 63);

        int copied = 0;
        while (copied < T) {                       // uniform loop
            int cnt = min(T - copied, SEGSZ - fofs);
            for (int r = w; r < nrows; r += 8) {   // wave w copies rows w,w+8,..
                int rofs = __shfl(excl, r);
                int rst  = __shfl(strt, r);
                int rln  = __shfl(rlen, r);
                int lo = max(rofs, copied), hi = min(rofs + rln, copied + cnt);
                for (int i = lo + lane; i < hi; i += 64) {
                    int dst = fofs + (i - copied);
                    int src = rst + (i - rofs);
                    sc[fseg][dst] = ckey[src];
                    sidx[fseg][dst] = src;
                }
            }
            fofs += cnt; copied += cnt;
            if (fofs == SEGSZ) {                   // uniform
                if (pend >= 0) STREAM_SEG(fseg ^ 1, pend);   // stream prev window's fill
                __syncthreads();                   // fill fseg done; stream fseg^1 done
                pend = SEGSZ;                      // just-filled seg = (new fseg)^1
                fseg ^= 1; fofs = 0;
            }
        }
    }
    if (pend >= 0) STREAM_SEG(fseg ^ 1, pend);     // uniform
    __syncthreads();                               // partial fill visible
    if (fofs > 0) STREAM_SEG(fseg, fofs);          // uniform
    __syncthreads();                               // sc reused as md/mi below

    md[(so * 32 + l) * 3 + 0] = e0;  mi[(so * 32 + l) * 3 + 0] = i0;
    md[(so * 32 + l) * 3 + 1] = e1;  mi[(so * 32 + l) * 3 + 1] = i1;
    md[(so * 32 + l) * 3 + 2] = e2;  mi[(so * 32 + l) * 3 + 2] = i2;
    __syncthreads();

    if (t < QPT) {
        float m0 = FINF, m1 = FINF, m2 = FINF;
        int   n0 = 0, n1 = 0, n2 = 0;
        #pragma unroll
        for (int ss = 0; ss < NST; ++ss) {
            int bx = (ss * 32 + t) * 3;
            INS3(md[bx],     mi[bx],     m0, m1, m2, n0, n1, n2);
            INS3(md[bx + 1], mi[bx + 1], m0, m1, m2, n0, n1, n2);
            INS3(md[bx + 2], mi[bx + 2], m0, m1, m2, n0, n1, n2);
        }
        // per-query margin: distance to own +-1-cell-box faces (grid-edge skipped)
        float mg = FINF;
        if (hx > 1)      mg = fminf(mg, qx - (GMIN + (hx - 1) * CS));
        if (hx < GS - 2) mg = fminf(mg, (GMIN + (hx + 2) * CS) - qx);
        if (hy > 1)      mg = fminf(mg, qy - (GMIN + (hy - 1) * CS));
        if (hy < GS - 2) mg = fminf(mg, (GMIN + (hy + 2) * CS) - qy);
        if (hz > 1)      mg = fminf(mg, qz - (GMIN + (hz - 1) * CS));
        if (hz < GS - 2) mg = fminf(mg, (GMIN + (hz + 2) * CS) - qz);
        if (m2 + qn <= mg * mg) {
            idw_write(qx, qy, qz, n0, n1, n2, ckey, cflow, out, b, origj);
        } else {
            int p = atomicAdd(&fbcnt[b], 1);
            fblist[b * NPTS + p] = ti * QPT + t;   // batch-local sorted position
        }
    }
}

// ---------------------------------------------------------------------------
// K3: wave-per-query fallback (R12/R17-proven), strided grid (1024 blocks).
// Lane ln scans candidates ln, ln+64, ... (coalesced vector loads),
// butterfly shfl merge, lane 0 writes.
// ---------------------------------------------------------------------------
__global__ __launch_bounds__(256) void fb_wave(
    const float4* __restrict__ qpos, const float4* __restrict__ ckey,
    const float4* __restrict__ cflow, const int* __restrict__ fbcnt,
    const int* __restrict__ fblist, float* __restrict__ out)
{
    int blk = blockIdx.x;                 // 1024 = BATCH * 256
    int b = blk >> 8, grp = blk & 255;
    int t = (int)threadIdx.x;
    int w = t >> 6, ln = t & 63;
    int cnt = fbcnt[b];

    for (int idx = grp * 4 + w; idx < cnt; idx += 1024) {   // wave-uniform
        int js = fblist[b * NPTS + idx];
        float4 qp = qpos[b * NPTS + js];
        float qx = qp.x, qy = qp.y, qz = qp.z;
        int origj = __float_as_int(qp.w);

        const float4* src = ckey + b * NPTS;

        float e0 = FINF, e1 = FINF, e2 = FINF;
        int   i0 = 0, i1 = 0, i2 = 0;
        #pragma unroll 4
        for (int k = ln; k < NPTS; k += 64) {
            float4 c = src[k];
            float d = fmaf(c.x, qx, fmaf(c.y, qy, fmaf(c.z, qz, c.w)));
            INS3(d, k, e0, e1, e2, i0, i1, i2);
        }
        #pragma unroll
        for (int o = 1; o < 64; o <<= 1) {
            float r0 = __shfl_xor(e0, o), r1 = __shfl_xor(e1, o), r2 = __shfl_xor(e2, o);
            int   s0 = __shfl_xor(i0, o), s1 = __shfl_xor(i1, o), s2 = __shfl_xor(i2, o);
            INS3(r0, s0, e0, e1, e2, i0, i1, i2);
            INS3(r1, s1, e0, e1, e2, i0, i1, i2);
            INS3(r2, s2, e0, e1, e2, i0, i1, i2);
        }
        if (ln == 0) {
            idw_write(qx, qy, qz, b * NPTS + i0, b * NPTS + i1, b * NPTS + i2,
                      ckey, cflow, out, b, origj);
        }
    }
}

// ---------------------------------------------------------------------------
// Launcher. 3 dispatches. Workspace ~1.9 MB.
// ---------------------------------------------------------------------------
extern "C" void kernel_launch(void* const* d_in, const int* in_sizes, int n_in,
                              void* d_out, int out_size, void* d_ws, size_t ws_size,
                              hipStream_t stream)
{
    const float* xyz1  = (const float*)d_in[0];
    const float* xyz2  = (const float*)d_in[1];
    const float* flow1 = (const float*)d_in[2];
    float* out = (float*)d_out;

    char* p = (char*)d_ws;
    float4* ckey   = (float4*)p;  p += (size_t)BATCH * NPTS * 16;
    float4* cflow  = (float4*)p;  p += (size_t)BATCH * NPTS * 16;
    float4* qpos   = (float4*)p;  p += (size_t)BATCH * NPTS * 16;
    int*    cstart = (int*)p;     p += (size_t)BATCH * NCP * 4;
    int*    fbcnt  = (int*)p;     p += 16;
    int*    fblist = (int*)p;

    sort_all<<<2 * BATCH, 1024, 0, stream>>>(xyz1, xyz2, flow1, ckey, cflow,
                                             qpos, cstart, fbcnt);
    knn_tile<<<BATCH * (NPTS / QPT), 512, 0, stream>>>(qpos, ckey, cflow,
                                                       cstart, fbcnt, fblist, out);
    fb_wave <<<BATCH * 256, 256, 0, stream>>>(qpos, ckey, cflow, fbcnt, fblist, out);
}